// Round 6
// baseline (741.489 us; speedup 1.0000x reference)
//
#include <hip/hip_runtime.h>
#include <stdint.h>

typedef unsigned short u16;
typedef unsigned int   u32;
typedef __attribute__((ext_vector_type(8))) short short8;   // 8 bf16 (4 VGPRs)
typedef __attribute__((ext_vector_type(4))) float float4v;  // 4 fp32 acc

#define DEV __device__ __forceinline__

DEV float bf2f(u16 u){ return __uint_as_float(((u32)u)<<16); }
DEV u16 f2bf(float f){
  u32 u = __float_as_uint(f);
  u32 r = u + 0x7fffu + ((u>>16)&1u);   // RNE
  return (u16)(r>>16);
}
DEV float gelu_f(float x){ return 0.5f*x*(1.0f + erff(x*0.70710678118654752f)); }
DEV float ldext(const void* b, size_t i, int f32){
  return f32 ? ((const float*)b)[i] : bf2f(((const u16*)b)[i]);
}
DEV int ld_src(const int* ei, int e, int E, int m64){ return m64 ? ei[2*e]     : ei[e]; }
DEV int ld_dst(const int* ei, int e, int E, int m64){ return m64 ? ei[2*(E+e)] : ei[E+e]; }
// MFMA B-operand swizzle: element (k,n) of a K x 64 weight -> fragment-contiguous index
DEV int swz(int k, int n){
  return (((k>>5)*4 + (n>>4))*64 + ((((k>>3)&3)<<4) | (n&15)))*8 + (k&7);
}

// ---------------------------------------------------------------- dtype detect
__global__ __launch_bounds__(256) void detect_types(const int* __restrict__ ei,
                                                    const u16* __restrict__ xw,
                                                    int* __restrict__ flags){
  __shared__ int a64, insane;
  int t = threadIdx.x;
  if (t==0){ a64=0; insane=0; }
  __syncthreads();
  int l=0;
  for (int i=t; i<4096; i+=256) l |= ei[2*i+1];
  if (l) atomicOr(&a64, 1);
  int c=0;
  for (int i=t; i<2048; i+=256){
    u16 lo = xw[2*i];
    int e8 = (lo>>7)&0xff;
    if (e8!=0 && (e8<90 || e8>160)) c++;
  }
  atomicAdd(&insane, c);
  __syncthreads();
  if (t==0){ flags[0] = a64?0:1; flags[1] = (insane>256)?1:0; }
}

// ---------------------------------------------------------------- x -> bf16 (only when fp32 input)
__global__ __launch_bounds__(256) void xconv(const void* __restrict__ x,
                                             const int* __restrict__ flags,
                                             u16* __restrict__ xbf, int total8){
  if (!flags[1]) return;   // bf16 input: GEMMs read x directly (xdelta)
  for (size_t i = (size_t)(blockIdx.x*256 + threadIdx.x)*8; i < (size_t)total8*8;
       i += (size_t)gridDim.x*256*8){
    const float* xf = (const float*)x + i;
    float4 a = *(const float4*)xf;
    float4 b = *(const float4*)(xf+4);
    u16 o[8];
    o[0]=f2bf(a.x); o[1]=f2bf(a.y); o[2]=f2bf(a.z); o[3]=f2bf(a.w);
    o[4]=f2bf(b.x); o[5]=f2bf(b.y); o[6]=f2bf(b.z); o[7]=f2bf(b.w);
    *(uint4*)(xbf + i) = *(uint4*)o;
  }
}

// ---------------------------------------------------------------- BN stats (vectorized + LDS reduce)
__global__ __launch_bounds__(256) void bn_stats(const void* __restrict__ x,
                                                const int* __restrict__ flags,
                                                float* __restrict__ sums, int N){
  __shared__ float red[16][128];
  int f32  = flags[1];
  int tid  = threadIdx.x;
  int col  = tid & 15;        // which 8-feature group
  int rsub = tid >> 4;        // 0..15
  float s8[8], q8[8];
  #pragma unroll
  for (int j=0;j<8;j++){ s8[j]=0.f; q8[j]=0.f; }
  for (int r = blockIdx.x*16 + rsub; r < N; r += gridDim.x*16){
    float f[8];
    if (f32){
      const float* xp = (const float*)x + (size_t)r*128 + col*8;
      float4 A = *(const float4*)xp;
      float4 B = *(const float4*)(xp+4);
      f[0]=A.x; f[1]=A.y; f[2]=A.z; f[3]=A.w;
      f[4]=B.x; f[5]=B.y; f[6]=B.z; f[7]=B.w;
    } else {
      const u16* xp = (const u16*)x + (size_t)r*128 + col*8;
      uint4 u = *(const uint4*)xp;
      f[0]=bf2f((u16)(u.x&0xffffu)); f[1]=bf2f((u16)(u.x>>16));
      f[2]=bf2f((u16)(u.y&0xffffu)); f[3]=bf2f((u16)(u.y>>16));
      f[4]=bf2f((u16)(u.z&0xffffu)); f[5]=bf2f((u16)(u.z>>16));
      f[6]=bf2f((u16)(u.w&0xffffu)); f[7]=bf2f((u16)(u.w>>16));
    }
    #pragma unroll
    for (int j=0;j<8;j++){ s8[j]+=f[j]; q8[j]+=f[j]*f[j]; }
  }
  #pragma unroll
  for (int j=0;j<8;j++) red[rsub][col*8+j] = s8[j];
  __syncthreads();
  if (tid < 128){
    float t=0.f;
    #pragma unroll
    for (int i=0;i<16;i++) t += red[i][tid];
    atomicAdd(&sums[tid], t);
  }
  __syncthreads();
  #pragma unroll
  for (int j=0;j<8;j++) red[rsub][col*8+j] = q8[j];
  __syncthreads();
  if (tid < 128){
    float t=0.f;
    #pragma unroll
    for (int i=0;i<16;i++) t += red[i][tid];
    atomicAdd(&sums[128+tid], t);
  }
}

// ---------------------------------------------------------------- degree count (XCD-partitioned by dst range)
__global__ __launch_bounds__(256) void edge_count(const int* __restrict__ ei, int E, int N,
                                                  const int* __restrict__ flags,
                                                  int* __restrict__ cnt){
  int m64 = flags[0];
  int part = blockIdx.x & 7;
  int lo = (int)((long)N*part/8), hi = (int)((long)N*(part+1)/8);
  int bid = blockIdx.x >> 3;
  int nb  = gridDim.x >> 3;
  for (int e = bid*256 + threadIdx.x; e < E; e += nb*256){
    int d = ld_dst(ei, e, E, m64);
    if (d >= lo && d < hi) atomicAdd(&cnt[d], 1);
  }
}

// ---------------------------------------------------------------- scan (CSR offsets)
#define SCAN_CHUNK 1024
__global__ __launch_bounds__(256) void scan_a(const int* __restrict__ cnt, int N,
                                              int* __restrict__ ofs, int* __restrict__ blksum,
                                              float* __restrict__ dis){
  __shared__ int lds[256];
  int t = threadIdx.x;
  int base = blockIdx.x*SCAN_CHUNK + t*4;
  int v[4];
  #pragma unroll
  for (int i=0;i<4;i++){ int idx=base+i; v[i] = (idx<N) ? cnt[idx] : 0; }
  #pragma unroll
  for (int i=0;i<4;i++){ int idx=base+i; if (idx<N) dis[idx] = v[i]>0 ? rsqrtf((float)v[i]) : 0.f; }
  int tsum = v[0]+v[1]+v[2]+v[3];
  lds[t] = tsum; __syncthreads();
  for (int off=1; off<256; off<<=1){
    int add = (t>=off) ? lds[t-off] : 0;
    __syncthreads();
    lds[t] += add;
    __syncthreads();
  }
  int run = lds[t] - tsum;
  #pragma unroll
  for (int i=0;i<4;i++){ int idx=base+i; if (idx<N) ofs[idx]=run; run += v[i]; }
  if (t==255) blksum[blockIdx.x] = lds[255];
}

__global__ void scan_b(const int* __restrict__ blksum, int nblk, int* __restrict__ blkoff){
  if (threadIdx.x==0 && blockIdx.x==0){
    int r=0;
    for (int i=0;i<nblk;i++){ blkoff[i]=r; r+=blksum[i]; }
  }
}

__global__ __launch_bounds__(256) void scan_c(int* __restrict__ ofs, const int* __restrict__ blkoff,
                                              int N, int E, int* __restrict__ cur){
  int i = blockIdx.x*256 + threadIdx.x;
  if (i < N){
    int v = ofs[i] + blkoff[i/SCAN_CHUNK];
    ofs[i] = v; cur[i] = v;
  }
  if (i==0) ofs[N] = E;
}

// ---------------------------------------------------------------- CSR scatter (XCD-partitioned by dst range)
__global__ __launch_bounds__(256) void edge_scatter(const int* __restrict__ ei, int E, int N,
                                                    const int* __restrict__ flags,
                                                    const float* __restrict__ dis,
                                                    int* __restrict__ cur, int* __restrict__ csrc,
                                                    float* __restrict__ cw){
  int m64 = flags[0];
  int part = blockIdx.x & 7;
  int lo = (int)((long)N*part/8), hi = (int)((long)N*(part+1)/8);
  int bid = blockIdx.x >> 3;
  int nb  = gridDim.x >> 3;
  for (int e = bid*256 + threadIdx.x; e < E; e += nb*256){
    int d = ld_dst(ei, e, E, m64);
    if (d < lo || d >= hi) continue;
    int s = ld_src(ei, e, E, m64);
    if ((unsigned)s >= (unsigned)N) continue;
    int p = atomicAdd(&cur[d], 1);
    if ((unsigned)p < (unsigned)E){
      csrc[p] = s;
      cw[p]   = dis[s]*dis[d];
    }
  }
}

// ---------------------------------------------------------------- weight prep (-> swizzled bf16 + fp32 bias)
struct PrepOut {
  u16 *W1p,*Wt1,*Wt2,*W2p,*W3a,*W3b,*W4p;
  float *b1p,*bt1,*bt2,*b2p,*b3a,*b3b,*b4p;
};

#define PREP_TOTAL 78272

__global__ __launch_bounds__(256) void prep(const float* __restrict__ sums, float invN,
    const int* __restrict__ flags,
    const void* g, const void* be,
    const void* W1, const void* b1,
    const void* t1W, const void* t1b,
    const void* W2, const void* b2,
    const void* t2W, const void* t2b,
    const void* W3, const void* b3,
    const void* W4, const void* b4,
    PrepOut o)
{
  int f32 = flags[1];
  int idx = blockIdx.x*256 + threadIdx.x;
  if (idx >= PREP_TOTAL) return;
  auto scale_shift = [&](int f, float& sc, float& sh){
    float m   = sums[f]*invN;
    float var = sums[128+f]*invN - m*m;
    sc = ldext(g,f,f32) * rsqrtf(var + 1e-5f);
    sh = ldext(be,f,f32) - m*sc;
  };
  if (idx < 8192){
    int k=idx>>6, n=idx&63; float sc,sh; scale_shift(k,sc,sh);
    o.W1p[swz(k,n)] = f2bf(sc*ldext(W1,idx,f32)); return;
  }
  idx -= 8192;
  if (idx < 64){
    float acc = ldext(b1,idx,f32);
    for (int f=0; f<128; f++){ float sc,sh; scale_shift(f,sc,sh); acc += sh*ldext(W1,f*64+idx,f32); }
    o.b1p[idx]=acc; return;
  }
  idx -= 64;
  if (idx < 16384){ int k=idx>>6,n=idx&63; o.Wt1[swz(k,n)]=f2bf(ldext(t1W,idx,f32)); return; }  idx -= 16384;
  if (idx < 64)   { o.bt1[idx]=ldext(t1b,idx,f32); return; }  idx -= 64;
  if (idx < 16384){ int k=idx>>6,n=idx&63; o.Wt2[swz(k,n)]=f2bf(ldext(t2W,idx,f32)); return; }  idx -= 16384;
  if (idx < 64)   { o.bt2[idx]=ldext(t2b,idx,f32); return; }  idx -= 64;
  if (idx < 4096) { int k=idx>>6,n=idx&63; o.W2p[swz(k,n)]=f2bf(ldext(W2,idx,f32));  return; }  idx -= 4096;
  if (idx < 64)   { o.b2p[idx]=ldext(b2,idx,f32);  return; }  idx -= 64;
  if (idx < 12288){ int k=idx>>6,n=idx&63; o.W3a[swz(k,n)]=f2bf(ldext(W3,(size_t)k*128+n,f32));    return; }  idx -= 12288;
  if (idx < 64)   { o.b3a[idx]=ldext(b3,idx,f32);  return; }  idx -= 64;
  if (idx < 12288){ int k=idx>>6,n=idx&63; o.W3b[swz(k,n)]=f2bf(ldext(W3,(size_t)k*128+64+n,f32)); return; }  idx -= 12288;
  if (idx < 64)   { o.b3b[idx]=ldext(b3,64+idx,f32); return; } idx -= 64;
  if (idx < 8192) { int k=idx>>6,n=idx&63; o.W4p[swz(k,n)]=f2bf(ldext(W4,idx,f32));  return; }
  else            { o.b4p[idx-8192]=ldext(b4,idx-8192,f32); }
}

// ---------------------------------------------------------------- MFMA GEMM
struct KD { const u16* p[8]; int ld[8]; };

template<int KS,int OUTMODE>
__global__ __launch_bounds__(256,2) void gemm_mfma(
    KD d, const u16* __restrict__ Wsw, const float* __restrict__ bias,
    void* __restrict__ out, int ldo, int ocol,
    int N, const int* __restrict__ flags, long xdelta, u32 xmask)
{
  constexpr int LBYTES = OUTMODE ? 128*68*4 : 128*72*2;
  __shared__ __align__(16) char lds[LBYTES];
  if (xmask && !flags[1]){
    #pragma unroll
    for (int t=0;t<KS;t++) if (xmask & (1u<<t)) d.p[t] += xdelta;
  }
  int tid = threadIdx.x, w = tid>>6, l = tid&63;
  int rlo = l&15, kq = l>>4;
  int row0b = blockIdx.x*128;
  int row0  = row0b + w*32;

  short8 Bf[KS][4];
  #pragma unroll
  for (int t=0;t<KS;t++)
    #pragma unroll
    for (int c=0;c<4;c++)
      Bf[t][c] = *(const short8*)(Wsw + ((t*4+c)*64 + l)*8);

  float4v a0[4], a1[4];
  #pragma unroll
  for (int c=0;c<4;c++){
    a0[c].x=0;a0[c].y=0;a0[c].z=0;a0[c].w=0;
    a1[c].x=0;a1[c].y=0;a1[c].z=0;a1[c].w=0;
  }

  #pragma unroll
  for (int t=0;t<KS;t++){
    const u16* ap = d.p[t]; int ld = d.ld[t];
    short8 A0 = *(const short8*)(ap + (size_t)(row0+rlo)*ld + kq*8);
    short8 A1 = *(const short8*)(ap + (size_t)(row0+16+rlo)*ld + kq*8);
    #pragma unroll
    for (int c=0;c<4;c++){
      a0[c] = __builtin_amdgcn_mfma_f32_16x16x32_bf16(A0, Bf[t][c], a0[c], 0,0,0);
      a1[c] = __builtin_amdgcn_mfma_f32_16x16x32_bf16(A1, Bf[t][c], a1[c], 0,0,0);
    }
  }

  float bv[4];
  #pragma unroll
  for (int c=0;c<4;c++) bv[c] = bias[c*16 + rlo];

  int nrow = N - row0b; if (nrow > 128) nrow = 128; if (nrow < 0) nrow = 0;

  if (OUTMODE==0){
    u16* s = (u16*)lds;
    #pragma unroll
    for (int c=0;c<4;c++){
      int col = c*16 + rlo;
      #pragma unroll
      for (int r=0;r<4;r++){
        s[(w*32 +      kq*4 + r)*72 + col] = f2bf(gelu_f(a0[c][r] + bv[c]));
        s[(w*32 + 16 + kq*4 + r)*72 + col] = f2bf(gelu_f(a1[c][r] + bv[c]));
      }
    }
    __syncthreads();
    u16* ob = (u16*)out + (size_t)row0b*ldo + ocol;
    for (int i=tid; i<nrow*8; i+=256){
      int r = i>>3, cc = (i&7)<<3;
      *(uint4*)(ob + (size_t)r*ldo + cc) = *(const uint4*)(s + r*72 + cc);
    }
  } else {
    int f32o = flags[1];
    if (f32o){
      float* sf = (float*)lds;
      #pragma unroll
      for (int c=0;c<4;c++){
        int col = c*16 + rlo;
        #pragma unroll
        for (int r=0;r<4;r++){
          float v0 = a0[c][r] + bv[c]; float v1 = a1[c][r] + bv[c];
          sf[(w*32 +      kq*4 + r)*68 + col] = isfinite(v0)?v0:777.0f;
          sf[(w*32 + 16 + kq*4 + r)*68 + col] = isfinite(v1)?v1:777.0f;
        }
      }
      __syncthreads();
      float* ob = (float*)out + (size_t)row0b*64;
      for (int i=tid; i<nrow*16; i+=256){
        int r = i>>4, cc = (i&15)<<2;
        *(uint4*)(ob + (size_t)r*64 + cc) = *(const uint4*)(sf + r*68 + cc);
      }
    } else {
      u16* s = (u16*)lds;
      #pragma unroll
      for (int c=0;c<4;c++){
        int col = c*16 + rlo;
        #pragma unroll
        for (int r=0;r<4;r++){
          float v0 = a0[c][r] + bv[c]; float v1 = a1[c][r] + bv[c];
          s[(w*32 +      kq*4 + r)*72 + col] = f2bf(isfinite(v0)?v0:777.0f);
          s[(w*32 + 16 + kq*4 + r)*72 + col] = f2bf(isfinite(v1)?v1:777.0f);
        }
      }
      __syncthreads();
      u16* ob = (u16*)out + (size_t)row0b*64;
      for (int i=tid; i<nrow*8; i+=256){
        int r = i>>3, cc = (i&7)<<3;
        *(uint4*)(ob + (size_t)r*64 + cc) = *(const uint4*)(s + r*72 + cc);
      }
    }
  }
}

// ---------------------------------------------------------------- SpMM: wave/dst-row, 16 lanes/neighbor (uint2 = 4 feats)
// 4 neighbor rows per load instruction; up to 32 gathers in flight.
__global__ __launch_bounds__(256) void spmm(const int* __restrict__ rofs,
    const int* __restrict__ csrc, const float* __restrict__ cw,
    const u16* __restrict__ hin, u16* __restrict__ hout, int N)
{
  int wid  = (blockIdx.x*256 + threadIdx.x) >> 6;
  int lane = threadIdx.x & 63;
  if (wid >= N) return;
  int g  = lane >> 4;          // neighbor group 0..3
  int fb = (lane & 15) * 4;    // feature base (4 features)
  int beg = rofs[wid], end = rofs[wid+1];
  float a[4] = {0.f,0.f,0.f,0.f};

  for (int e0=beg; e0<end; e0+=64){
    int cnt = end - e0; if (cnt > 64) cnt = 64;
    int s = 0; float w = 0.f;
    if (lane < cnt){ s = csrc[e0+lane]; w = cw[e0+lane]; }
    int j0 = 0;
    for (; j0+32 <= cnt; j0 += 32){
      uint2 v[8]; float ww[8];
      #pragma unroll
      for (int i=0;i<8;i++){
        int j = j0 + i*4 + g;
        int   sj = __shfl(s, j);
        float wj = __shfl(w, j);
        ww[i] = wj;
        int sr = ((unsigned)sj < (unsigned)N) ? sj : 0;
        v[i] = *(const uint2*)(hin + (size_t)sr*64 + fb);
      }
      #pragma unroll
      for (int i=0;i<8;i++){
        u32 lo=v[i].x, hi=v[i].y; float ws=ww[i];
        a[0] += ws*bf2f((u16)(lo&0xffffu));
        a[1] += ws*bf2f((u16)(lo>>16));
        a[2] += ws*bf2f((u16)(hi&0xffffu));
        a[3] += ws*bf2f((u16)(hi>>16));
      }
    }
    if (j0 < cnt){
      int nb = cnt - j0, ni = (nb+3)>>2;
      uint2 v[8]; float ww[8];
      for (int i=0;i<ni;i++){
        int j = j0 + i*4 + g;
        int   sj = __shfl(s, j & 63);
        float wj = __shfl(w, j & 63);
        bool ok = j < cnt;
        ww[i] = ok ? wj : 0.f;
        int sr = (ok && (unsigned)sj < (unsigned)N) ? sj : 0;
        v[i] = *(const uint2*)(hin + (size_t)sr*64 + fb);
      }
      for (int i=0;i<ni;i++){
        u32 lo=v[i].x, hi=v[i].y; float ws=ww[i];
        a[0] += ws*bf2f((u16)(lo&0xffffu));
        a[1] += ws*bf2f((u16)(lo>>16));
        a[2] += ws*bf2f((u16)(hi&0xffffu));
        a[3] += ws*bf2f((u16)(hi>>16));
      }
    }
  }
  #pragma unroll
  for (int k=0;k<4;k++){
    a[k] += __shfl_xor(a[k], 16);
    a[k] += __shfl_xor(a[k], 32);
  }
  if (lane < 16){
    u16 o[4] = { f2bf(a[0]), f2bf(a[1]), f2bf(a[2]), f2bf(a[3]) };
    *(uint2*)(hout + (size_t)wid*64 + fb) = *(uint2*)o;
  }
}

// ---------------------------------------------------------------- launch
extern "C" void kernel_launch(void* const* d_in, const int* in_sizes, int n_in,
                              void* d_out, int out_size, void* d_ws, size_t ws_size,
                              hipStream_t stream)
{
  const void* x   = d_in[0];
  const int*  ei  = (const int*)d_in[1];
  const void* gam = d_in[2];  const void* bet = d_in[3];
  const void* W1  = d_in[4];  const void* b1  = d_in[5];
  const void* t1W = d_in[6];  const void* t1b = d_in[7];
  const void* W2  = d_in[8];  const void* b2  = d_in[9];
  const void* t2W = d_in[10]; const void* t2b = d_in[11];
  const void* W3  = d_in[12]; const void* b3  = d_in[13];
  const void* W4  = d_in[14]; const void* b4  = d_in[15];

  const int N = in_sizes[0]/128;
  const int E = in_sizes[1]/2;

  char* p = (char*)d_ws;
  auto carve = [&](size_t bytes)->void*{
    void* r = (void*)p;
    p += (bytes + 255) & ~(size_t)255;
    return r;
  };
  int*   row_cnt = (int*)  carve((size_t)N*4);       // reused as row_cur after scan
  float* bnsums  = (float*)carve(256*4);
  int*   flags   = (int*)  carve(256);
  size_t zero_span = (size_t)((char*)flags + 256 - (char*)row_cnt);
  int*   row_ofs = (int*)  carve((size_t)(N+1)*4);
  int*   blksum  = (int*)  carve(1024*4);
  int*   blkoff  = (int*)  carve(1024*4);
  float* dis     = (float*)carve((size_t)N*4);
  int*   csrc    = (int*)  carve((size_t)E*4);
  float* cw      = (float*)carve((size_t)E*4);
  PrepOut po;
  po.W1p=(u16*)carve(8192*2);   po.b1p=(float*)carve(64*4);
  po.Wt1=(u16*)carve(16384*2);  po.bt1=(float*)carve(64*4);
  po.Wt2=(u16*)carve(16384*2);  po.bt2=(float*)carve(64*4);
  po.W2p=(u16*)carve(4096*2);   po.b2p=(float*)carve(64*4);
  po.W3a=(u16*)carve(12288*2);  po.b3a=(float*)carve(64*4);
  po.W3b=(u16*)carve(12288*2);  po.b3b=(float*)carve(64*4);
  po.W4p=(u16*)carve(8192*2);   po.b4p=(float*)carve(64*4);
  u16* xbf  = (u16*)carve((size_t)N*128*2);
  u16* buf0 = (u16*)carve((size_t)N*64*2);   // sizes 256B-divisible -> contiguous
  u16* buf1 = (u16*)carve((size_t)N*64*2);
  u16* buf2 = (u16*)carve((size_t)N*64*2);
  u16* buf3 = (u16*)carve((size_t)N*64*2);
  u16* buf4 = (u16*)carve((size_t)N*64*2);
  carve(64*1024);                            // guard: MFMA tail rows may over-read
  u16* Ka   = buf0;                          // N x 128 bf16, spans buf0+buf1

  size_t needed = (size_t)(p - (char*)d_ws);
  if (needed > ws_size){
    hipMemsetAsync(d_out, 0, (size_t)out_size*2, stream);
    return;
  }

  long xdelta = (const u16*)x - xbf;         // element delta: bf16 path reads x directly

  const int nchunk = (N + SCAN_CHUNK-1)/SCAN_CHUNK;
  const int rblk   = (N + 255)/256;
  const int gblk   = (N + 127)/128;
  const int sblk   = (N + 3)/4;

  hipMemsetAsync(row_cnt, 0, zero_span, stream);

  detect_types<<<1, 256, 0, stream>>>(ei, (const u16*)x, flags);
  bn_stats    <<<512,256,0, stream>>>(x, flags, bnsums, N);
  edge_count  <<<2048,256,0,stream>>>(ei, E, N, flags, row_cnt);
  scan_a      <<<nchunk,256,0,stream>>>(row_cnt, N, row_ofs, blksum, dis);
  scan_b      <<<1,  64, 0, stream>>>(blksum, nchunk, blkoff);
  scan_c      <<<rblk,256,0, stream>>>(row_ofs, blkoff, N, E, row_cnt);
  edge_scatter<<<2048,256,0,stream>>>(ei, E, N, flags, dis, row_cnt, csrc, cw);
  prep        <<<(PREP_TOTAL+255)/256, 256, 0, stream>>>(bnsums, 1.0f/(float)N, flags,
                 gam, bet, W1, b1, t1W, t1b, W2, b2, t2W, t2b, W3, b3, W4, b4, po);
  xconv       <<<4096,256,0,stream>>>(x, flags, xbf, N*16);

  KD dx;   for (int t=0;t<4;t++){ dx.p[t]  = xbf + t*32;  dx.ld[t]=128; }
           for (int t=4;t<8;t++){ dx.p[t]  = xbf;         dx.ld[t]=128; }
  KD dcat; { u16* bs[4]={buf0,buf1,buf2,buf3};
             for (int t=0;t<8;t++){ dcat.p[t]=bs[t>>1]+(t&1)*32; dcat.ld[t]=64; } }
  KD d3;   for (int t=0;t<4;t++){ d3.p[t]  = xbf + t*32;  d3.ld[t]=128; }
           d3.p[4]=buf4; d3.ld[4]=64; d3.p[5]=buf4+32; d3.ld[5]=64;
           d3.p[6]=buf4; d3.ld[6]=64; d3.p[7]=buf4;    d3.ld[7]=64;
  KD d4;   for (int t=0;t<4;t++){ d4.p[t]  = Ka + t*32;   d4.ld[t]=128; }
           for (int t=4;t<8;t++){ d4.p[t]  = Ka;          d4.ld[t]=128; }

  // L1: A(buf0) = gelu(BN(x) @ W1 + b1)
  gemm_mfma<4,0><<<gblk,256,0,stream>>>(dx, po.W1p, po.b1p, buf0,64,0, N, flags, xdelta, 0xFu);
  // TAG1 hops
  spmm<<<sblk,256,0,stream>>>(row_ofs, csrc, cw, buf0, buf1, N);
  spmm<<<sblk,256,0,stream>>>(row_ofs, csrc, cw, buf1, buf2, N);
  spmm<<<sblk,256,0,stream>>>(row_ofs, csrc, cw, buf2, buf3, N);
  // TAG1 concat-GEMM: E(buf4) = gelu([A|Ah|A2h|A3h] @ Wt1 + bt1)
  gemm_mfma<8,0><<<gblk,256,0,stream>>>(dcat, po.Wt1, po.bt1, buf4,64,0, N, flags, 0, 0);
  // L2: F(buf0) = gelu(E @ W2 + b2)
  { KD dl2; for (int t=0;t<8;t++){ dl2.p[t]=buf4+(t&1)*32; dl2.ld[t]=64; }
    gemm_mfma<2,0><<<gblk,256,0,stream>>>(dl2, po.W2p, po.b2p, buf0,64,0, N, flags, 0, 0); }
  // TAG2 hops
  spmm<<<sblk,256,0,stream>>>(row_ofs, csrc, cw, buf0, buf1, N);
  spmm<<<sblk,256,0,stream>>>(row_ofs, csrc, cw, buf1, buf2, N);
  spmm<<<sblk,256,0,stream>>>(row_ofs, csrc, cw, buf2, buf3, N);
  // TAG2 concat-GEMM: J(buf4) = gelu([F|G|H|I] @ Wt2 + bt2)
  gemm_mfma<8,0><<<gblk,256,0,stream>>>(dcat, po.Wt2, po.bt2, buf4,64,0, N, flags, 0, 0);
  // L3: Ka = gelu([x|J] @ W3 + b3), two 64-col halves (Ka overlays buf0+buf1)
  gemm_mfma<6,0><<<gblk,256,0,stream>>>(d3, po.W3a, po.b3a, Ka,128,0,  N, flags, xdelta, 0xFu);
  gemm_mfma<6,0><<<gblk,256,0,stream>>>(d3, po.W3b, po.b3b, Ka,128,64, N, flags, xdelta, 0xFu);
  // L4: out = Ka @ W4 + b4
  gemm_mfma<4,1><<<gblk,256,0,stream>>>(d4, po.W4p, po.b4p, d_out,64,0, N, flags, 0, 0);
}

// Round 7
// 619.375 us; speedup vs baseline: 1.1972x; 1.1972x over previous
//
#include <hip/hip_runtime.h>
#include <stdint.h>

typedef unsigned short u16;
typedef unsigned int   u32;
typedef __attribute__((ext_vector_type(8))) short short8;   // 8 bf16 (4 VGPRs)
typedef __attribute__((ext_vector_type(4))) float float4v;  // 4 fp32 acc

#define DEV __device__ __forceinline__

DEV float bf2f(u16 u){ return __uint_as_float(((u32)u)<<16); }
DEV u16 f2bf(float f){
  u32 u = __float_as_uint(f);
  u32 r = u + 0x7fffu + ((u>>16)&1u);   // RNE
  return (u16)(r>>16);
}
DEV float gelu_f(float x){ return 0.5f*x*(1.0f + erff(x*0.70710678118654752f)); }
DEV float ldext(const void* b, size_t i, int f32){
  return f32 ? ((const float*)b)[i] : bf2f(((const u16*)b)[i]);
}
DEV int ld_src(const int* ei, int e, int E, int m64){ return m64 ? ei[2*e]     : ei[e]; }
DEV int ld_dst(const int* ei, int e, int E, int m64){ return m64 ? ei[2*(E+e)] : ei[E+e]; }
// MFMA B-operand swizzle: element (k,n) of a K x 64 weight -> fragment-contiguous index
DEV int swz(int k, int n){
  return (((k>>5)*4 + (n>>4))*64 + ((((k>>3)&3)<<4) | (n&15)))*8 + (k&7);
}

// ---------------------------------------------------------------- dtype detect
__global__ __launch_bounds__(256) void detect_types(const int* __restrict__ ei,
                                                    const u16* __restrict__ xw,
                                                    int* __restrict__ flags){
  __shared__ int a64, insane;
  int t = threadIdx.x;
  if (t==0){ a64=0; insane=0; }
  __syncthreads();
  int l=0;
  for (int i=t; i<4096; i+=256) l |= ei[2*i+1];
  if (l) atomicOr(&a64, 1);
  int c=0;
  for (int i=t; i<2048; i+=256){
    u16 lo = xw[2*i];
    int e8 = (lo>>7)&0xff;
    if (e8!=0 && (e8<90 || e8>160)) c++;
  }
  atomicAdd(&insane, c);
  __syncthreads();
  if (t==0){ flags[0] = a64?0:1; flags[1] = (insane>256)?1:0; }
}

// ---------------------------------------------------------------- x -> bf16 (only when fp32 input)
__global__ __launch_bounds__(256) void xconv(const void* __restrict__ x,
                                             const int* __restrict__ flags,
                                             u16* __restrict__ xbf, int total8){
  if (!flags[1]) return;   // bf16 input: GEMMs read x directly (xdelta)
  for (size_t i = (size_t)(blockIdx.x*256 + threadIdx.x)*8; i < (size_t)total8*8;
       i += (size_t)gridDim.x*256*8){
    const float* xf = (const float*)x + i;
    float4 a = *(const float4*)xf;
    float4 b = *(const float4*)(xf+4);
    u16 o[8];
    o[0]=f2bf(a.x); o[1]=f2bf(a.y); o[2]=f2bf(a.z); o[3]=f2bf(a.w);
    o[4]=f2bf(b.x); o[5]=f2bf(b.y); o[6]=f2bf(b.z); o[7]=f2bf(b.w);
    *(uint4*)(xbf + i) = *(uint4*)o;
  }
}

// ---------------------------------------------------------------- BN stats (vectorized + LDS reduce)
__global__ __launch_bounds__(256) void bn_stats(const void* __restrict__ x,
                                                const int* __restrict__ flags,
                                                float* __restrict__ sums, int N){
  __shared__ float red[16][128];
  int f32  = flags[1];
  int tid  = threadIdx.x;
  int col  = tid & 15;        // which 8-feature group
  int rsub = tid >> 4;        // 0..15
  float s8[8], q8[8];
  #pragma unroll
  for (int j=0;j<8;j++){ s8[j]=0.f; q8[j]=0.f; }
  for (int r = blockIdx.x*16 + rsub; r < N; r += gridDim.x*16){
    float f[8];
    if (f32){
      const float* xp = (const float*)x + (size_t)r*128 + col*8;
      float4 A = *(const float4*)xp;
      float4 B = *(const float4*)(xp+4);
      f[0]=A.x; f[1]=A.y; f[2]=A.z; f[3]=A.w;
      f[4]=B.x; f[5]=B.y; f[6]=B.z; f[7]=B.w;
    } else {
      const u16* xp = (const u16*)x + (size_t)r*128 + col*8;
      uint4 u = *(const uint4*)xp;
      f[0]=bf2f((u16)(u.x&0xffffu)); f[1]=bf2f((u16)(u.x>>16));
      f[2]=bf2f((u16)(u.y&0xffffu)); f[3]=bf2f((u16)(u.y>>16));
      f[4]=bf2f((u16)(u.z&0xffffu)); f[5]=bf2f((u16)(u.z>>16));
      f[6]=bf2f((u16)(u.w&0xffffu)); f[7]=bf2f((u16)(u.w>>16));
    }
    #pragma unroll
    for (int j=0;j<8;j++){ s8[j]+=f[j]; q8[j]+=f[j]*f[j]; }
  }
  #pragma unroll
  for (int j=0;j<8;j++) red[rsub][col*8+j] = s8[j];
  __syncthreads();
  if (tid < 128){
    float t=0.f;
    #pragma unroll
    for (int i=0;i<16;i++) t += red[i][tid];
    atomicAdd(&sums[tid], t);
  }
  __syncthreads();
  #pragma unroll
  for (int j=0;j<8;j++) red[rsub][col*8+j] = q8[j];
  __syncthreads();
  if (tid < 128){
    float t=0.f;
    #pragma unroll
    for (int i=0;i<16;i++) t += red[i][tid];
    atomicAdd(&sums[128+tid], t);
  }
}

// ---------------------------------------------------------------- degree count (XCD-partitioned by dst range)
__global__ __launch_bounds__(256) void edge_count(const int* __restrict__ ei, int E, int N,
                                                  const int* __restrict__ flags,
                                                  int* __restrict__ cnt){
  int m64 = flags[0];
  int part = blockIdx.x & 7;
  int lo = (int)((long)N*part/8), hi = (int)((long)N*(part+1)/8);
  int bid = blockIdx.x >> 3;
  int nb  = gridDim.x >> 3;
  for (int e = bid*256 + threadIdx.x; e < E; e += nb*256){
    int d = ld_dst(ei, e, E, m64);
    if (d >= lo && d < hi) atomicAdd(&cnt[d], 1);
  }
}

// ---------------------------------------------------------------- scan (CSR offsets)
#define SCAN_CHUNK 1024
__global__ __launch_bounds__(256) void scan_a(const int* __restrict__ cnt, int N,
                                              int* __restrict__ ofs, int* __restrict__ blksum,
                                              float* __restrict__ dis){
  __shared__ int lds[256];
  int t = threadIdx.x;
  int base = blockIdx.x*SCAN_CHUNK + t*4;
  int v[4];
  #pragma unroll
  for (int i=0;i<4;i++){ int idx=base+i; v[i] = (idx<N) ? cnt[idx] : 0; }
  #pragma unroll
  for (int i=0;i<4;i++){ int idx=base+i; if (idx<N) dis[idx] = v[i]>0 ? rsqrtf((float)v[i]) : 0.f; }
  int tsum = v[0]+v[1]+v[2]+v[3];
  lds[t] = tsum; __syncthreads();
  for (int off=1; off<256; off<<=1){
    int add = (t>=off) ? lds[t-off] : 0;
    __syncthreads();
    lds[t] += add;
    __syncthreads();
  }
  int run = lds[t] - tsum;
  #pragma unroll
  for (int i=0;i<4;i++){ int idx=base+i; if (idx<N) ofs[idx]=run; run += v[i]; }
  if (t==255) blksum[blockIdx.x] = lds[255];
}

__global__ void scan_b(const int* __restrict__ blksum, int nblk, int* __restrict__ blkoff){
  if (threadIdx.x==0 && blockIdx.x==0){
    int r=0;
    for (int i=0;i<nblk;i++){ blkoff[i]=r; r+=blksum[i]; }
  }
}

__global__ __launch_bounds__(256) void scan_c(int* __restrict__ ofs, const int* __restrict__ blkoff,
                                              int N, int E, int* __restrict__ cur){
  int i = blockIdx.x*256 + threadIdx.x;
  if (i < N){
    int v = ofs[i] + blkoff[i/SCAN_CHUNK];
    ofs[i] = v; cur[i] = v;
  }
  if (i==0) ofs[N] = E;
}

// ---------------------------------------------------------------- CSR scatter (XCD-partitioned by dst range)
__global__ __launch_bounds__(256) void edge_scatter(const int* __restrict__ ei, int E, int N,
                                                    const int* __restrict__ flags,
                                                    const float* __restrict__ dis,
                                                    int* __restrict__ cur, int* __restrict__ csrc,
                                                    float* __restrict__ cw){
  int m64 = flags[0];
  int part = blockIdx.x & 7;
  int lo = (int)((long)N*part/8), hi = (int)((long)N*(part+1)/8);
  int bid = blockIdx.x >> 3;
  int nb  = gridDim.x >> 3;
  for (int e = bid*256 + threadIdx.x; e < E; e += nb*256){
    int d = ld_dst(ei, e, E, m64);
    if (d < lo || d >= hi) continue;
    int s = ld_src(ei, e, E, m64);
    if ((unsigned)s >= (unsigned)N) continue;
    int p = atomicAdd(&cur[d], 1);
    if ((unsigned)p < (unsigned)E){
      csrc[p] = s;
      cw[p]   = dis[s]*dis[d];
    }
  }
}

// ---------------------------------------------------------------- weight prep (-> swizzled bf16 + fp32 bias)
struct PrepOut {
  u16 *W1p,*Wt1,*Wt2,*W2p,*W3a,*W3b,*W4p;
  float *b1p,*bt1,*bt2,*b2p,*b3a,*b3b,*b4p;
};

#define PREP_TOTAL 78272

__global__ __launch_bounds__(256) void prep(const float* __restrict__ sums, float invN,
    const int* __restrict__ flags,
    const void* g, const void* be,
    const void* W1, const void* b1,
    const void* t1W, const void* t1b,
    const void* W2, const void* b2,
    const void* t2W, const void* t2b,
    const void* W3, const void* b3,
    const void* W4, const void* b4,
    PrepOut o)
{
  int f32 = flags[1];
  int idx = blockIdx.x*256 + threadIdx.x;
  if (idx >= PREP_TOTAL) return;
  auto scale_shift = [&](int f, float& sc, float& sh){
    float m   = sums[f]*invN;
    float var = sums[128+f]*invN - m*m;
    sc = ldext(g,f,f32) * rsqrtf(var + 1e-5f);
    sh = ldext(be,f,f32) - m*sc;
  };
  if (idx < 8192){
    int k=idx>>6, n=idx&63; float sc,sh; scale_shift(k,sc,sh);
    o.W1p[swz(k,n)] = f2bf(sc*ldext(W1,idx,f32)); return;
  }
  idx -= 8192;
  if (idx < 64){
    float acc = ldext(b1,idx,f32);
    for (int f=0; f<128; f++){ float sc,sh; scale_shift(f,sc,sh); acc += sh*ldext(W1,f*64+idx,f32); }
    o.b1p[idx]=acc; return;
  }
  idx -= 64;
  if (idx < 16384){ int k=idx>>6,n=idx&63; o.Wt1[swz(k,n)]=f2bf(ldext(t1W,idx,f32)); return; }  idx -= 16384;
  if (idx < 64)   { o.bt1[idx]=ldext(t1b,idx,f32); return; }  idx -= 64;
  if (idx < 16384){ int k=idx>>6,n=idx&63; o.Wt2[swz(k,n)]=f2bf(ldext(t2W,idx,f32)); return; }  idx -= 16384;
  if (idx < 64)   { o.bt2[idx]=ldext(t2b,idx,f32); return; }  idx -= 64;
  if (idx < 4096) { int k=idx>>6,n=idx&63; o.W2p[swz(k,n)]=f2bf(ldext(W2,idx,f32));  return; }  idx -= 4096;
  if (idx < 64)   { o.b2p[idx]=ldext(b2,idx,f32);  return; }  idx -= 64;
  if (idx < 12288){ int k=idx>>6,n=idx&63; o.W3a[swz(k,n)]=f2bf(ldext(W3,(size_t)k*128+n,f32));    return; }  idx -= 12288;
  if (idx < 64)   { o.b3a[idx]=ldext(b3,idx,f32);  return; }  idx -= 64;
  if (idx < 12288){ int k=idx>>6,n=idx&63; o.W3b[swz(k,n)]=f2bf(ldext(W3,(size_t)k*128+64+n,f32)); return; }  idx -= 12288;
  if (idx < 64)   { o.b3b[idx]=ldext(b3,64+idx,f32); return; } idx -= 64;
  if (idx < 8192) { int k=idx>>6,n=idx&63; o.W4p[swz(k,n)]=f2bf(ldext(W4,idx,f32));  return; }
  else            { o.b4p[idx-8192]=ldext(b4,idx-8192,f32); }
}

// ---------------------------------------------------------------- MFMA GEMM
struct KD { const u16* p[8]; int ld[8]; };

template<int KS,int OUTMODE>
__global__ __launch_bounds__(256,2) void gemm_mfma(
    KD d, const u16* __restrict__ Wsw, const float* __restrict__ bias,
    void* __restrict__ out, int ldo, int ocol,
    int N, const int* __restrict__ flags, long xdelta, u32 xmask)
{
  constexpr int LBYTES = OUTMODE ? 128*68*4 : 128*72*2;
  __shared__ __align__(16) char lds[LBYTES];
  if (xmask && !flags[1]){
    #pragma unroll
    for (int t=0;t<KS;t++) if (xmask & (1u<<t)) d.p[t] += xdelta;
  }
  int tid = threadIdx.x, w = tid>>6, l = tid&63;
  int rlo = l&15, kq = l>>4;
  int row0b = blockIdx.x*128;
  int row0  = row0b + w*32;

  short8 Bf[KS][4];
  #pragma unroll
  for (int t=0;t<KS;t++)
    #pragma unroll
    for (int c=0;c<4;c++)
      Bf[t][c] = *(const short8*)(Wsw + ((t*4+c)*64 + l)*8);

  float4v a0[4], a1[4];
  #pragma unroll
  for (int c=0;c<4;c++){
    a0[c].x=0;a0[c].y=0;a0[c].z=0;a0[c].w=0;
    a1[c].x=0;a1[c].y=0;a1[c].z=0;a1[c].w=0;
  }

  #pragma unroll
  for (int t=0;t<KS;t++){
    const u16* ap = d.p[t]; int ld = d.ld[t];
    short8 A0 = *(const short8*)(ap + (size_t)(row0+rlo)*ld + kq*8);
    short8 A1 = *(const short8*)(ap + (size_t)(row0+16+rlo)*ld + kq*8);
    #pragma unroll
    for (int c=0;c<4;c++){
      a0[c] = __builtin_amdgcn_mfma_f32_16x16x32_bf16(A0, Bf[t][c], a0[c], 0,0,0);
      a1[c] = __builtin_amdgcn_mfma_f32_16x16x32_bf16(A1, Bf[t][c], a1[c], 0,0,0);
    }
  }

  float bv[4];
  #pragma unroll
  for (int c=0;c<4;c++) bv[c] = bias[c*16 + rlo];

  int nrow = N - row0b; if (nrow > 128) nrow = 128; if (nrow < 0) nrow = 0;

  if (OUTMODE==0){
    u16* s = (u16*)lds;
    #pragma unroll
    for (int c=0;c<4;c++){
      int col = c*16 + rlo;
      #pragma unroll
      for (int r=0;r<4;r++){
        s[(w*32 +      kq*4 + r)*72 + col] = f2bf(gelu_f(a0[c][r] + bv[c]));
        s[(w*32 + 16 + kq*4 + r)*72 + col] = f2bf(gelu_f(a1[c][r] + bv[c]));
      }
    }
    __syncthreads();
    u16* ob = (u16*)out + (size_t)row0b*ldo + ocol;
    for (int i=tid; i<nrow*8; i+=256){
      int r = i>>3, cc = (i&7)<<3;
      *(uint4*)(ob + (size_t)r*ldo + cc) = *(const uint4*)(s + r*72 + cc);
    }
  } else {
    int f32o = flags[1];
    if (f32o){
      float* sf = (float*)lds;
      #pragma unroll
      for (int c=0;c<4;c++){
        int col = c*16 + rlo;
        #pragma unroll
        for (int r=0;r<4;r++){
          float v0 = a0[c][r] + bv[c]; float v1 = a1[c][r] + bv[c];
          sf[(w*32 +      kq*4 + r)*68 + col] = isfinite(v0)?v0:777.0f;
          sf[(w*32 + 16 + kq*4 + r)*68 + col] = isfinite(v1)?v1:777.0f;
        }
      }
      __syncthreads();
      float* ob = (float*)out + (size_t)row0b*64;
      for (int i=tid; i<nrow*16; i+=256){
        int r = i>>4, cc = (i&15)<<2;
        *(uint4*)(ob + (size_t)r*64 + cc) = *(const uint4*)(sf + r*68 + cc);
      }
    } else {
      u16* s = (u16*)lds;
      #pragma unroll
      for (int c=0;c<4;c++){
        int col = c*16 + rlo;
        #pragma unroll
        for (int r=0;r<4;r++){
          float v0 = a0[c][r] + bv[c]; float v1 = a1[c][r] + bv[c];
          s[(w*32 +      kq*4 + r)*72 + col] = f2bf(isfinite(v0)?v0:777.0f);
          s[(w*32 + 16 + kq*4 + r)*72 + col] = f2bf(isfinite(v1)?v1:777.0f);
        }
      }
      __syncthreads();
      u16* ob = (u16*)out + (size_t)row0b*64;
      for (int i=tid; i<nrow*8; i+=256){
        int r = i>>3, cc = (i&7)<<3;
        *(uint4*)(ob + (size_t)r*64 + cc) = *(const uint4*)(s + r*72 + cc);
      }
    }
  }
}

// ---------------------------------------------------------------- SpMM: wave/dst-row, lane=feature.
// wid forced wave-uniform -> rofs/csrc/cw go through the SCALAR pipe (s_load);
// per neighbor the vector pipe does: 1 coalesced 128B row load + shift + fmac(sgpr w).
__global__ __launch_bounds__(256) void spmm(const int* __restrict__ rofs,
    const int* __restrict__ csrc, const float* __restrict__ cw,
    const u16* __restrict__ hin, u16* __restrict__ hout, int N)
{
  int wid  = __builtin_amdgcn_readfirstlane((int)((blockIdx.x*256 + threadIdx.x) >> 6));
  int lane = threadIdx.x & 63;
  if (wid >= N) return;
  int beg = rofs[wid], end = rofs[wid+1];   // uniform -> s_load
  float a = 0.f;
  int e = beg;
  for (; e + 8 <= end; e += 8){
    int sa[8]; float wa[8]; float va[8];
    #pragma unroll
    for (int i=0;i<8;i++){ sa[i] = csrc[e+i]; wa[i] = cw[e+i]; }   // scalar loads
    #pragma unroll
    for (int i=0;i<8;i++){
      int s = ((u32)sa[i] < (u32)N) ? sa[i] : 0;                   // s_cselect
      va[i] = bf2f(hin[(size_t)s*64 + lane]);                      // sgpr base + lane
    }
    #pragma unroll
    for (int i=0;i<8;i++) a += wa[i]*va[i];                        // v_fmac v,s,v
  }
  for (; e < end; ++e){
    int s = csrc[e]; float w = cw[e];
    if ((u32)s >= (u32)N) s = 0;
    a += w*bf2f(hin[(size_t)s*64 + lane]);
  }
  hout[(size_t)wid*64 + lane] = f2bf(a);
}

// ---------------------------------------------------------------- launch
extern "C" void kernel_launch(void* const* d_in, const int* in_sizes, int n_in,
                              void* d_out, int out_size, void* d_ws, size_t ws_size,
                              hipStream_t stream)
{
  const void* x   = d_in[0];
  const int*  ei  = (const int*)d_in[1];
  const void* gam = d_in[2];  const void* bet = d_in[3];
  const void* W1  = d_in[4];  const void* b1  = d_in[5];
  const void* t1W = d_in[6];  const void* t1b = d_in[7];
  const void* W2  = d_in[8];  const void* b2  = d_in[9];
  const void* t2W = d_in[10]; const void* t2b = d_in[11];
  const void* W3  = d_in[12]; const void* b3  = d_in[13];
  const void* W4  = d_in[14]; const void* b4  = d_in[15];

  const int N = in_sizes[0]/128;
  const int E = in_sizes[1]/2;

  char* p = (char*)d_ws;
  auto carve = [&](size_t bytes)->void*{
    void* r = (void*)p;
    p += (bytes + 255) & ~(size_t)255;
    return r;
  };
  int*   row_cnt = (int*)  carve((size_t)N*4);       // reused as row_cur after scan
  float* bnsums  = (float*)carve(256*4);
  int*   flags   = (int*)  carve(256);
  size_t zero_span = (size_t)((char*)flags + 256 - (char*)row_cnt);
  int*   row_ofs = (int*)  carve((size_t)(N+1)*4);
  int*   blksum  = (int*)  carve(1024*4);
  int*   blkoff  = (int*)  carve(1024*4);
  float* dis     = (float*)carve((size_t)N*4);
  int*   csrc    = (int*)  carve((size_t)E*4);
  float* cw      = (float*)carve((size_t)E*4);
  PrepOut po;
  po.W1p=(u16*)carve(8192*2);   po.b1p=(float*)carve(64*4);
  po.Wt1=(u16*)carve(16384*2);  po.bt1=(float*)carve(64*4);
  po.Wt2=(u16*)carve(16384*2);  po.bt2=(float*)carve(64*4);
  po.W2p=(u16*)carve(4096*2);   po.b2p=(float*)carve(64*4);
  po.W3a=(u16*)carve(12288*2);  po.b3a=(float*)carve(64*4);
  po.W3b=(u16*)carve(12288*2);  po.b3b=(float*)carve(64*4);
  po.W4p=(u16*)carve(8192*2);   po.b4p=(float*)carve(64*4);
  u16* xbf  = (u16*)carve((size_t)N*128*2);
  u16* buf0 = (u16*)carve((size_t)N*64*2);   // sizes 256B-divisible -> contiguous
  u16* buf1 = (u16*)carve((size_t)N*64*2);
  u16* buf2 = (u16*)carve((size_t)N*64*2);
  u16* buf3 = (u16*)carve((size_t)N*64*2);
  u16* buf4 = (u16*)carve((size_t)N*64*2);
  carve(64*1024);                            // guard: MFMA tail rows may over-read
  u16* Ka   = buf0;                          // N x 128 bf16, spans buf0+buf1

  size_t needed = (size_t)(p - (char*)d_ws);
  if (needed > ws_size){
    hipMemsetAsync(d_out, 0, (size_t)out_size*2, stream);
    return;
  }

  long xdelta = (const u16*)x - xbf;         // element delta: bf16 path reads x directly

  const int nchunk = (N + SCAN_CHUNK-1)/SCAN_CHUNK;
  const int rblk   = (N + 255)/256;
  const int gblk   = (N + 127)/128;
  const int sblk   = (N + 3)/4;

  hipMemsetAsync(row_cnt, 0, zero_span, stream);

  detect_types<<<1, 256, 0, stream>>>(ei, (const u16*)x, flags);
  bn_stats    <<<512,256,0, stream>>>(x, flags, bnsums, N);
  edge_count  <<<2048,256,0,stream>>>(ei, E, N, flags, row_cnt);
  scan_a      <<<nchunk,256,0,stream>>>(row_cnt, N, row_ofs, blksum, dis);
  scan_b      <<<1,  64, 0, stream>>>(blksum, nchunk, blkoff);
  scan_c      <<<rblk,256,0, stream>>>(row_ofs, blkoff, N, E, row_cnt);
  edge_scatter<<<2048,256,0,stream>>>(ei, E, N, flags, dis, row_cnt, csrc, cw);
  prep        <<<(PREP_TOTAL+255)/256, 256, 0, stream>>>(bnsums, 1.0f/(float)N, flags,
                 gam, bet, W1, b1, t1W, t1b, W2, b2, t2W, t2b, W3, b3, W4, b4, po);
  xconv       <<<4096,256,0,stream>>>(x, flags, xbf, N*16);

  KD dx;   for (int t=0;t<4;t++){ dx.p[t]  = xbf + t*32;  dx.ld[t]=128; }
           for (int t=4;t<8;t++){ dx.p[t]  = xbf;         dx.ld[t]=128; }
  KD dcat; { u16* bs[4]={buf0,buf1,buf2,buf3};
             for (int t=0;t<8;t++){ dcat.p[t]=bs[t>>1]+(t&1)*32; dcat.ld[t]=64; } }
  KD d3;   for (int t=0;t<4;t++){ d3.p[t]  = xbf + t*32;  d3.ld[t]=128; }
           d3.p[4]=buf4; d3.ld[4]=64; d3.p[5]=buf4+32; d3.ld[5]=64;
           d3.p[6]=buf4; d3.ld[6]=64; d3.p[7]=buf4;    d3.ld[7]=64;
  KD d4;   for (int t=0;t<4;t++){ d4.p[t]  = Ka + t*32;   d4.ld[t]=128; }
           for (int t=4;t<8;t++){ d4.p[t]  = Ka;          d4.ld[t]=128; }

  // L1: A(buf0) = gelu(BN(x) @ W1 + b1)
  gemm_mfma<4,0><<<gblk,256,0,stream>>>(dx, po.W1p, po.b1p, buf0,64,0, N, flags, xdelta, 0xFu);
  // TAG1 hops
  spmm<<<sblk,256,0,stream>>>(row_ofs, csrc, cw, buf0, buf1, N);
  spmm<<<sblk,256,0,stream>>>(row_ofs, csrc, cw, buf1, buf2, N);
  spmm<<<sblk,256,0,stream>>>(row_ofs, csrc, cw, buf2, buf3, N);
  // TAG1 concat-GEMM: E(buf4) = gelu([A|Ah|A2h|A3h] @ Wt1 + bt1)
  gemm_mfma<8,0><<<gblk,256,0,stream>>>(dcat, po.Wt1, po.bt1, buf4,64,0, N, flags, 0, 0);
  // L2: F(buf0) = gelu(E @ W2 + b2)
  { KD dl2; for (int t=0;t<8;t++){ dl2.p[t]=buf4+(t&1)*32; dl2.ld[t]=64; }
    gemm_mfma<2,0><<<gblk,256,0,stream>>>(dl2, po.W2p, po.b2p, buf0,64,0, N, flags, 0, 0); }
  // TAG2 hops
  spmm<<<sblk,256,0,stream>>>(row_ofs, csrc, cw, buf0, buf1, N);
  spmm<<<sblk,256,0,stream>>>(row_ofs, csrc, cw, buf1, buf2, N);
  spmm<<<sblk,256,0,stream>>>(row_ofs, csrc, cw, buf2, buf3, N);
  // TAG2 concat-GEMM: J(buf4) = gelu([F|G|H|I] @ Wt2 + bt2)
  gemm_mfma<8,0><<<gblk,256,0,stream>>>(dcat, po.Wt2, po.bt2, buf4,64,0, N, flags, 0, 0);
  // L3: Ka = gelu([x|J] @ W3 + b3), two 64-col halves (Ka overlays buf0+buf1)
  gemm_mfma<6,0><<<gblk,256,0,stream>>>(d3, po.W3a, po.b3a, Ka,128,0,  N, flags, xdelta, 0xFu);
  gemm_mfma<6,0><<<gblk,256,0,stream>>>(d3, po.W3b, po.b3b, Ka,128,64, N, flags, xdelta, 0xFu);
  // L4: out = Ka @ W4 + b4
  gemm_mfma<4,1><<<gblk,256,0,stream>>>(d4, po.W4p, po.b4p, d_out,64,0, N, flags, 0, 0);
}

// Round 8
// 531.445 us; speedup vs baseline: 1.3952x; 1.1655x over previous
//
#include <hip/hip_runtime.h>
#include <stdint.h>

typedef unsigned short u16;
typedef unsigned int   u32;
typedef __attribute__((ext_vector_type(8))) short short8;   // 8 bf16 (4 VGPRs)
typedef __attribute__((ext_vector_type(4))) float float4v;  // 4 fp32 acc

#define DEV __device__ __forceinline__

DEV float bf2f(u16 u){ return __uint_as_float(((u32)u)<<16); }
DEV u16 f2bf(float f){
  u32 u = __float_as_uint(f);
  u32 r = u + 0x7fffu + ((u>>16)&1u);   // RNE
  return (u16)(r>>16);
}
DEV float gelu_f(float x){ return 0.5f*x*(1.0f + erff(x*0.70710678118654752f)); }
DEV float ldext(const void* b, size_t i, int f32){
  return f32 ? ((const float*)b)[i] : bf2f(((const u16*)b)[i]);
}
DEV int ld_src(const int* ei, int e, int E, int m64){ return m64 ? ei[2*e]     : ei[e]; }
DEV int ld_dst(const int* ei, int e, int E, int m64){ return m64 ? ei[2*(E+e)] : ei[E+e]; }
// MFMA B-operand swizzle: element (k,n) of a K x 64 weight -> fragment-contiguous index
DEV int swz(int k, int n){
  return (((k>>5)*4 + (n>>4))*64 + ((((k>>3)&3)<<4) | (n&15)))*8 + (k&7);
}

// ---------------------------------------------------------------- dtype detect
__global__ __launch_bounds__(256) void detect_types(const int* __restrict__ ei,
                                                    const u16* __restrict__ xw,
                                                    int* __restrict__ flags){
  __shared__ int a64, insane;
  int t = threadIdx.x;
  if (t==0){ a64=0; insane=0; }
  __syncthreads();
  int l=0;
  for (int i=t; i<4096; i+=256) l |= ei[2*i+1];
  if (l) atomicOr(&a64, 1);
  int c=0;
  for (int i=t; i<2048; i+=256){
    u16 lo = xw[2*i];
    int e8 = (lo>>7)&0xff;
    if (e8!=0 && (e8<90 || e8>160)) c++;
  }
  atomicAdd(&insane, c);
  __syncthreads();
  if (t==0){ flags[0] = a64?0:1; flags[1] = (insane>256)?1:0; }
}

// ---------------------------------------------------------------- edge_index -> int32 (single pass over int64)
__global__ __launch_bounds__(256) void econv(const int* __restrict__ ei,
                                             const int* __restrict__ flags,
                                             int* __restrict__ s32, int* __restrict__ d32, int E){
  int m64 = flags[0];
  for (int e = blockIdx.x*256 + threadIdx.x; e < E; e += gridDim.x*256){
    s32[e] = ld_src(ei, e, E, m64);
    d32[e] = ld_dst(ei, e, E, m64);
  }
}

// ---------------------------------------------------------------- x -> bf16 (only when fp32 input)
__global__ __launch_bounds__(256) void xconv(const void* __restrict__ x,
                                             const int* __restrict__ flags,
                                             u16* __restrict__ xbf, int total8){
  if (!flags[1]) return;   // bf16 input: GEMMs read x directly (xdelta)
  for (size_t i = (size_t)(blockIdx.x*256 + threadIdx.x)*8; i < (size_t)total8*8;
       i += (size_t)gridDim.x*256*8){
    const float* xf = (const float*)x + i;
    float4 a = *(const float4*)xf;
    float4 b = *(const float4*)(xf+4);
    u16 o[8];
    o[0]=f2bf(a.x); o[1]=f2bf(a.y); o[2]=f2bf(a.z); o[3]=f2bf(a.w);
    o[4]=f2bf(b.x); o[5]=f2bf(b.y); o[6]=f2bf(b.z); o[7]=f2bf(b.w);
    *(uint4*)(xbf + i) = *(uint4*)o;
  }
}

// ---------------------------------------------------------------- BN stats (vectorized + LDS reduce)
__global__ __launch_bounds__(256) void bn_stats(const void* __restrict__ x,
                                                const int* __restrict__ flags,
                                                float* __restrict__ sums, int N){
  __shared__ float red[16][128];
  int f32  = flags[1];
  int tid  = threadIdx.x;
  int col  = tid & 15;
  int rsub = tid >> 4;
  float s8[8], q8[8];
  #pragma unroll
  for (int j=0;j<8;j++){ s8[j]=0.f; q8[j]=0.f; }
  for (int r = blockIdx.x*16 + rsub; r < N; r += gridDim.x*16){
    float f[8];
    if (f32){
      const float* xp = (const float*)x + (size_t)r*128 + col*8;
      float4 A = *(const float4*)xp;
      float4 B = *(const float4*)(xp+4);
      f[0]=A.x; f[1]=A.y; f[2]=A.z; f[3]=A.w;
      f[4]=B.x; f[5]=B.y; f[6]=B.z; f[7]=B.w;
    } else {
      const u16* xp = (const u16*)x + (size_t)r*128 + col*8;
      uint4 u = *(const uint4*)xp;
      f[0]=bf2f((u16)(u.x&0xffffu)); f[1]=bf2f((u16)(u.x>>16));
      f[2]=bf2f((u16)(u.y&0xffffu)); f[3]=bf2f((u16)(u.y>>16));
      f[4]=bf2f((u16)(u.z&0xffffu)); f[5]=bf2f((u16)(u.z>>16));
      f[6]=bf2f((u16)(u.w&0xffffu)); f[7]=bf2f((u16)(u.w>>16));
    }
    #pragma unroll
    for (int j=0;j<8;j++){ s8[j]+=f[j]; q8[j]+=f[j]*f[j]; }
  }
  #pragma unroll
  for (int j=0;j<8;j++) red[rsub][col*8+j] = s8[j];
  __syncthreads();
  if (tid < 128){
    float t=0.f;
    #pragma unroll
    for (int i=0;i<16;i++) t += red[i][tid];
    atomicAdd(&sums[tid], t);
  }
  __syncthreads();
  #pragma unroll
  for (int j=0;j<8;j++) red[rsub][col*8+j] = q8[j];
  __syncthreads();
  if (tid < 128){
    float t=0.f;
    #pragma unroll
    for (int i=0;i<16;i++) t += red[i][tid];
    atomicAdd(&sums[128+tid], t);
  }
}

// ---------------------------------------------------------------- degree count (XCD-partitioned, int32 dst)
__global__ __launch_bounds__(256) void edge_count(const int* __restrict__ d32, int E, int N,
                                                  int* __restrict__ cnt){
  int part = blockIdx.x & 7;
  int lo = (int)((long)N*part/8), hi = (int)((long)N*(part+1)/8);
  int bid = blockIdx.x >> 3;
  int nb  = gridDim.x >> 3;
  for (int e = bid*256 + threadIdx.x; e < E; e += nb*256){
    int d = d32[e];
    if (d >= lo && d < hi) atomicAdd(&cnt[d], 1);
  }
}

// ---------------------------------------------------------------- scan (CSR offsets)
#define SCAN_CHUNK 1024
__global__ __launch_bounds__(256) void scan_a(const int* __restrict__ cnt, int N,
                                              int* __restrict__ ofs, int* __restrict__ blksum,
                                              float* __restrict__ dis){
  __shared__ int lds[256];
  int t = threadIdx.x;
  int base = blockIdx.x*SCAN_CHUNK + t*4;
  int v[4];
  #pragma unroll
  for (int i=0;i<4;i++){ int idx=base+i; v[i] = (idx<N) ? cnt[idx] : 0; }
  #pragma unroll
  for (int i=0;i<4;i++){ int idx=base+i; if (idx<N) dis[idx] = v[i]>0 ? rsqrtf((float)v[i]) : 0.f; }
  int tsum = v[0]+v[1]+v[2]+v[3];
  lds[t] = tsum; __syncthreads();
  for (int off=1; off<256; off<<=1){
    int add = (t>=off) ? lds[t-off] : 0;
    __syncthreads();
    lds[t] += add;
    __syncthreads();
  }
  int run = lds[t] - tsum;
  #pragma unroll
  for (int i=0;i<4;i++){ int idx=base+i; if (idx<N) ofs[idx]=run; run += v[i]; }
  if (t==255) blksum[blockIdx.x] = lds[255];
}

__global__ void scan_b(const int* __restrict__ blksum, int nblk, int* __restrict__ blkoff){
  if (threadIdx.x==0 && blockIdx.x==0){
    int r=0;
    for (int i=0;i<nblk;i++){ blkoff[i]=r; r+=blksum[i]; }
  }
}

__global__ __launch_bounds__(256) void scan_c(int* __restrict__ ofs, const int* __restrict__ blkoff,
                                              int N, int E, int* __restrict__ cur){
  int i = blockIdx.x*256 + threadIdx.x;
  if (i < N){
    int v = ofs[i] + blkoff[i/SCAN_CHUNK];
    ofs[i] = v; cur[i] = v;
  }
  if (i==0) ofs[N] = E;
}

// ---------------------------------------------------------------- CSR scatter (XCD-partitioned, packed (src,w))
__global__ __launch_bounds__(256) void edge_scatter(const int* __restrict__ s32,
                                                    const int* __restrict__ d32, int E, int N,
                                                    const float* __restrict__ dis,
                                                    int* __restrict__ cur, int2* __restrict__ epack){
  int part = blockIdx.x & 7;
  int lo = (int)((long)N*part/8), hi = (int)((long)N*(part+1)/8);
  int bid = blockIdx.x >> 3;
  int nb  = gridDim.x >> 3;
  for (int e = bid*256 + threadIdx.x; e < E; e += nb*256){
    int d = d32[e];
    if (d < lo || d >= hi) continue;
    int s = s32[e];
    if ((unsigned)s >= (unsigned)N) continue;
    int p = atomicAdd(&cur[d], 1);
    if ((unsigned)p < (unsigned)E){
      int2 pk; pk.x = s; pk.y = __float_as_int(dis[s]*dis[d]);
      epack[p] = pk;
    }
  }
}

// ---------------------------------------------------------------- weight prep (-> swizzled bf16 + fp32 bias)
struct PrepOut {
  u16 *W1p,*Wt1,*Wt2,*W2p,*W3a,*W3b,*W4p;
  float *b1p,*bt1,*bt2,*b2p,*b3a,*b3b,*b4p;
};

#define PREP_TOTAL 78272

__global__ __launch_bounds__(256) void prep(const float* __restrict__ sums, float invN,
    const int* __restrict__ flags,
    const void* g, const void* be,
    const void* W1, const void* b1,
    const void* t1W, const void* t1b,
    const void* W2, const void* b2,
    const void* t2W, const void* t2b,
    const void* W3, const void* b3,
    const void* W4, const void* b4,
    PrepOut o)
{
  int f32 = flags[1];
  int idx = blockIdx.x*256 + threadIdx.x;
  if (idx >= PREP_TOTAL) return;
  auto scale_shift = [&](int f, float& sc, float& sh){
    float m   = sums[f]*invN;
    float var = sums[128+f]*invN - m*m;
    sc = ldext(g,f,f32) * rsqrtf(var + 1e-5f);
    sh = ldext(be,f,f32) - m*sc;
  };
  if (idx < 8192){
    int k=idx>>6, n=idx&63; float sc,sh; scale_shift(k,sc,sh);
    o.W1p[swz(k,n)] = f2bf(sc*ldext(W1,idx,f32)); return;
  }
  idx -= 8192;
  if (idx < 64){
    float acc = ldext(b1,idx,f32);
    for (int f=0; f<128; f++){ float sc,sh; scale_shift(f,sc,sh); acc += sh*ldext(W1,f*64+idx,f32); }
    o.b1p[idx]=acc; return;
  }
  idx -= 64;
  if (idx < 16384){ int k=idx>>6,n=idx&63; o.Wt1[swz(k,n)]=f2bf(ldext(t1W,idx,f32)); return; }  idx -= 16384;
  if (idx < 64)   { o.bt1[idx]=ldext(t1b,idx,f32); return; }  idx -= 64;
  if (idx < 16384){ int k=idx>>6,n=idx&63; o.Wt2[swz(k,n)]=f2bf(ldext(t2W,idx,f32)); return; }  idx -= 16384;
  if (idx < 64)   { o.bt2[idx]=ldext(t2b,idx,f32); return; }  idx -= 64;
  if (idx < 4096) { int k=idx>>6,n=idx&63; o.W2p[swz(k,n)]=f2bf(ldext(W2,idx,f32));  return; }  idx -= 4096;
  if (idx < 64)   { o.b2p[idx]=ldext(b2,idx,f32);  return; }  idx -= 64;
  if (idx < 12288){ int k=idx>>6,n=idx&63; o.W3a[swz(k,n)]=f2bf(ldext(W3,(size_t)k*128+n,f32));    return; }  idx -= 12288;
  if (idx < 64)   { o.b3a[idx]=ldext(b3,idx,f32);  return; }  idx -= 64;
  if (idx < 12288){ int k=idx>>6,n=idx&63; o.W3b[swz(k,n)]=f2bf(ldext(W3,(size_t)k*128+64+n,f32)); return; }  idx -= 12288;
  if (idx < 64)   { o.b3b[idx]=ldext(b3,64+idx,f32); return; } idx -= 64;
  if (idx < 8192) { int k=idx>>6,n=idx&63; o.W4p[swz(k,n)]=f2bf(ldext(W4,idx,f32));  return; }
  else            { o.b4p[idx-8192]=ldext(b4,idx-8192,f32); }
}

// ---------------------------------------------------------------- MFMA GEMM
struct KD { const u16* p[8]; int ld[8]; };

template<int KS,int OUTMODE>
__global__ __launch_bounds__(256,2) void gemm_mfma(
    KD d, const u16* __restrict__ Wsw, const float* __restrict__ bias,
    void* __restrict__ out, int ldo, int ocol,
    int N, const int* __restrict__ flags, long xdelta, u32 xmask)
{
  constexpr int LBYTES = OUTMODE ? 128*68*4 : 128*72*2;
  __shared__ __align__(16) char lds[LBYTES];
  if (xmask && !flags[1]){
    #pragma unroll
    for (int t=0;t<KS;t++) if (xmask & (1u<<t)) d.p[t] += xdelta;
  }
  int tid = threadIdx.x, w = tid>>6, l = tid&63;
  int rlo = l&15, kq = l>>4;
  int row0b = blockIdx.x*128;
  int row0  = row0b + w*32;

  short8 Bf[KS][4];
  #pragma unroll
  for (int t=0;t<KS;t++)
    #pragma unroll
    for (int c=0;c<4;c++)
      Bf[t][c] = *(const short8*)(Wsw + ((t*4+c)*64 + l)*8);

  float4v a0[4], a1[4];
  #pragma unroll
  for (int c=0;c<4;c++){
    a0[c].x=0;a0[c].y=0;a0[c].z=0;a0[c].w=0;
    a1[c].x=0;a1[c].y=0;a1[c].z=0;a1[c].w=0;
  }

  #pragma unroll
  for (int t=0;t<KS;t++){
    const u16* ap = d.p[t]; int ld = d.ld[t];
    short8 A0 = *(const short8*)(ap + (size_t)(row0+rlo)*ld + kq*8);
    short8 A1 = *(const short8*)(ap + (size_t)(row0+16+rlo)*ld + kq*8);
    #pragma unroll
    for (int c=0;c<4;c++){
      a0[c] = __builtin_amdgcn_mfma_f32_16x16x32_bf16(A0, Bf[t][c], a0[c], 0,0,0);
      a1[c] = __builtin_amdgcn_mfma_f32_16x16x32_bf16(A1, Bf[t][c], a1[c], 0,0,0);
    }
  }

  float bv[4];
  #pragma unroll
  for (int c=0;c<4;c++) bv[c] = bias[c*16 + rlo];

  int nrow = N - row0b; if (nrow > 128) nrow = 128; if (nrow < 0) nrow = 0;

  if (OUTMODE==0){
    u16* s = (u16*)lds;
    #pragma unroll
    for (int c=0;c<4;c++){
      int col = c*16 + rlo;
      #pragma unroll
      for (int r=0;r<4;r++){
        s[(w*32 +      kq*4 + r)*72 + col] = f2bf(gelu_f(a0[c][r] + bv[c]));
        s[(w*32 + 16 + kq*4 + r)*72 + col] = f2bf(gelu_f(a1[c][r] + bv[c]));
      }
    }
    __syncthreads();
    u16* ob = (u16*)out + (size_t)row0b*ldo + ocol;
    for (int i=tid; i<nrow*8; i+=256){
      int r = i>>3, cc = (i&7)<<3;
      *(uint4*)(ob + (size_t)r*ldo + cc) = *(const uint4*)(s + r*72 + cc);
    }
  } else {
    int f32o = flags[1];
    if (f32o){
      float* sf = (float*)lds;
      #pragma unroll
      for (int c=0;c<4;c++){
        int col = c*16 + rlo;
        #pragma unroll
        for (int r=0;r<4;r++){
          float v0 = a0[c][r] + bv[c]; float v1 = a1[c][r] + bv[c];
          sf[(w*32 +      kq*4 + r)*68 + col] = isfinite(v0)?v0:777.0f;
          sf[(w*32 + 16 + kq*4 + r)*68 + col] = isfinite(v1)?v1:777.0f;
        }
      }
      __syncthreads();
      float* ob = (float*)out + (size_t)row0b*64;
      for (int i=tid; i<nrow*16; i+=256){
        int r = i>>4, cc = (i&15)<<2;
        *(uint4*)(ob + (size_t)r*64 + cc) = *(const uint4*)(sf + r*68 + cc);
      }
    } else {
      u16* s = (u16*)lds;
      #pragma unroll
      for (int c=0;c<4;c++){
        int col = c*16 + rlo;
        #pragma unroll
        for (int r=0;r<4;r++){
          float v0 = a0[c][r] + bv[c]; float v1 = a1[c][r] + bv[c];
          s[(w*32 +      kq*4 + r)*72 + col] = f2bf(isfinite(v0)?v0:777.0f);
          s[(w*32 + 16 + kq*4 + r)*72 + col] = f2bf(isfinite(v1)?v1:777.0f);
        }
      }
      __syncthreads();
      u16* ob = (u16*)out + (size_t)row0b*64;
      for (int i=tid; i<nrow*8; i+=256){
        int r = i>>3, cc = (i&7)<<3;
        *(uint4*)(ob + (size_t)r*64 + cc) = *(const uint4*)(s + r*72 + cc);
      }
    }
  }
}

// ---------------------------------------------------------------- SpMM: 8 rows per wave, 8 lanes/row, uint4 = 8 feats/lane
// Each gather instruction moves 64 lanes x 16B = 1KB covering 8 different rows.
// Index/weight packed as int2, prefetched 1 iteration ahead. No cross-lane ops.
__global__ __launch_bounds__(256) void spmm(const int* __restrict__ rofs,
    const int2* __restrict__ epack,
    const u16* __restrict__ hin, u16* __restrict__ hout, int N)
{
  int lane = threadIdx.x & 63;
  int wv   = (int)((blockIdx.x*256 + threadIdx.x) >> 6);
  int sub  = lane >> 3;          // 0..7 : which row of the 8
  int f8   = (lane & 7) * 8;     // feature octet base
  int row  = wv*8 + sub;
  bool rok = row < N;
  int beg = rok ? rofs[row]   : 0;
  int end = rok ? rofs[row+1] : 0;

  float acc[8];
  #pragma unroll
  for (int j=0;j<8;j++) acc[j]=0.f;

  int e = beg;
  int2 pk; pk.x = 0; pk.y = 0;
  if (e < end) pk = epack[e];

  while (__any(e < end)){
    bool act = e < end;
    int   s = act ? pk.x : 0;
    float w = act ? __int_as_float(pk.y) : 0.f;
    if ((u32)s >= (u32)N){ s = 0; w = 0.f; }
    uint4 v = *(const uint4*)(hin + (size_t)s*64 + f8);
    int e1 = e + 1;
    if (e1 < end) pk = epack[e1];
    acc[0] += w*__uint_as_float(v.x<<16);
    acc[1] += w*__uint_as_float(v.x&0xffff0000u);
    acc[2] += w*__uint_as_float(v.y<<16);
    acc[3] += w*__uint_as_float(v.y&0xffff0000u);
    acc[4] += w*__uint_as_float(v.z<<16);
    acc[5] += w*__uint_as_float(v.z&0xffff0000u);
    acc[6] += w*__uint_as_float(v.w<<16);
    acc[7] += w*__uint_as_float(v.w&0xffff0000u);
    e = e1;
  }

  if (rok){
    u16 o[8];
    #pragma unroll
    for (int j=0;j<8;j++) o[j]=f2bf(acc[j]);
    *(uint4*)(hout + (size_t)row*64 + f8) = *(uint4*)o;
  }
}

// ---------------------------------------------------------------- launch
extern "C" void kernel_launch(void* const* d_in, const int* in_sizes, int n_in,
                              void* d_out, int out_size, void* d_ws, size_t ws_size,
                              hipStream_t stream)
{
  const void* x   = d_in[0];
  const int*  ei  = (const int*)d_in[1];
  const void* gam = d_in[2];  const void* bet = d_in[3];
  const void* W1  = d_in[4];  const void* b1  = d_in[5];
  const void* t1W = d_in[6];  const void* t1b = d_in[7];
  const void* W2  = d_in[8];  const void* b2  = d_in[9];
  const void* t2W = d_in[10]; const void* t2b = d_in[11];
  const void* W3  = d_in[12]; const void* b3  = d_in[13];
  const void* W4  = d_in[14]; const void* b4  = d_in[15];

  const int N = in_sizes[0]/128;
  const int E = in_sizes[1]/2;

  char* p = (char*)d_ws;
  auto carve = [&](size_t bytes)->void*{
    void* r = (void*)p;
    p += (bytes + 255) & ~(size_t)255;
    return r;
  };
  int*   row_cnt = (int*)  carve((size_t)N*4);       // reused as row_cur after scan
  float* bnsums  = (float*)carve(256*4);
  int*   flags   = (int*)  carve(256);
  size_t zero_span = (size_t)((char*)flags + 256 - (char*)row_cnt);
  int*   row_ofs = (int*)  carve((size_t)(N+1)*4);
  int*   blksum  = (int*)  carve(1024*4);
  int*   blkoff  = (int*)  carve(1024*4);
  float* dis     = (float*)carve((size_t)N*4);
  int*   src32   = (int*)  carve((size_t)E*4);
  int*   dst32   = (int*)  carve((size_t)E*4);
  int2*  epack   = (int2*) carve((size_t)E*8);
  PrepOut po;
  po.W1p=(u16*)carve(8192*2);   po.b1p=(float*)carve(64*4);
  po.Wt1=(u16*)carve(16384*2);  po.bt1=(float*)carve(64*4);
  po.Wt2=(u16*)carve(16384*2);  po.bt2=(float*)carve(64*4);
  po.W2p=(u16*)carve(4096*2);   po.b2p=(float*)carve(64*4);
  po.W3a=(u16*)carve(12288*2);  po.b3a=(float*)carve(64*4);
  po.W3b=(u16*)carve(12288*2);  po.b3b=(float*)carve(64*4);
  po.W4p=(u16*)carve(8192*2);   po.b4p=(float*)carve(64*4);
  u16* xbf  = (u16*)carve((size_t)N*128*2);
  u16* buf0 = (u16*)carve((size_t)N*64*2);   // sizes 256B-divisible -> contiguous
  u16* buf1 = (u16*)carve((size_t)N*64*2);
  u16* buf2 = (u16*)carve((size_t)N*64*2);
  u16* buf3 = (u16*)carve((size_t)N*64*2);
  u16* buf4 = (u16*)carve((size_t)N*64*2);
  carve(64*1024);                            // guard: MFMA tail rows may over-read
  u16* Ka   = buf0;                          // N x 128 bf16, spans buf0+buf1

  size_t needed = (size_t)(p - (char*)d_ws);
  if (needed > ws_size){
    hipMemsetAsync(d_out, 0, (size_t)out_size*2, stream);
    return;
  }

  long xdelta = (const u16*)x - xbf;         // element delta: bf16 path reads x directly

  const int nchunk = (N + SCAN_CHUNK-1)/SCAN_CHUNK;
  const int rblk   = (N + 255)/256;
  const int gblk   = (N + 127)/128;
  const int sblk   = (N + 31)/32;            // spmm: 32 rows per block (4 waves x 8)

  hipMemsetAsync(row_cnt, 0, zero_span, stream);

  detect_types<<<1, 256, 0, stream>>>(ei, (const u16*)x, flags);
  econv       <<<2048,256,0,stream>>>(ei, flags, src32, dst32, E);
  bn_stats    <<<512,256,0, stream>>>(x, flags, bnsums, N);
  edge_count  <<<2048,256,0,stream>>>(dst32, E, N, row_cnt);
  scan_a      <<<nchunk,256,0,stream>>>(row_cnt, N, row_ofs, blksum, dis);
  scan_b      <<<1,  64, 0, stream>>>(blksum, nchunk, blkoff);
  scan_c      <<<rblk,256,0, stream>>>(row_ofs, blkoff, N, E, row_cnt);
  edge_scatter<<<2048,256,0,stream>>>(src32, dst32, E, N, dis, row_cnt, epack);
  prep        <<<(PREP_TOTAL+255)/256, 256, 0, stream>>>(bnsums, 1.0f/(float)N, flags,
                 gam, bet, W1, b1, t1W, t1b, W2, b2, t2W, t2b, W3, b3, W4, b4, po);
  xconv       <<<4096,256,0,stream>>>(x, flags, xbf, N*16);

  KD dx;   for (int t=0;t<4;t++){ dx.p[t]  = xbf + t*32;  dx.ld[t]=128; }
           for (int t=4;t<8;t++){ dx.p[t]  = xbf;         dx.ld[t]=128; }
  KD dcat; { u16* bs[4]={buf0,buf1,buf2,buf3};
             for (int t=0;t<8;t++){ dcat.p[t]=bs[t>>1]+(t&1)*32; dcat.ld[t]=64; } }
  KD d3;   for (int t=0;t<4;t++){ d3.p[t]  = xbf + t*32;  d3.ld[t]=128; }
           d3.p[4]=buf4; d3.ld[4]=64; d3.p[5]=buf4+32; d3.ld[5]=64;
           d3.p[6]=buf4; d3.ld[6]=64; d3.p[7]=buf4;    d3.ld[7]=64;
  KD d4;   for (int t=0;t<4;t++){ d4.p[t]  = Ka + t*32;   d4.ld[t]=128; }
           for (int t=4;t<8;t++){ d4.p[t]  = Ka;          d4.ld[t]=128; }

  // L1: A(buf0) = gelu(BN(x) @ W1 + b1)
  gemm_mfma<4,0><<<gblk,256,0,stream>>>(dx, po.W1p, po.b1p, buf0,64,0, N, flags, xdelta, 0xFu);
  // TAG1 hops
  spmm<<<sblk,256,0,stream>>>(row_ofs, epack, buf0, buf1, N);
  spmm<<<sblk,256,0,stream>>>(row_ofs, epack, buf1, buf2, N);
  spmm<<<sblk,256,0,stream>>>(row_ofs, epack, buf2, buf3, N);
  // TAG1 concat-GEMM: E(buf4) = gelu([A|Ah|A2h|A3h] @ Wt1 + bt1)
  gemm_mfma<8,0><<<gblk,256,0,stream>>>(dcat, po.Wt1, po.bt1, buf4,64,0, N, flags, 0, 0);
  // L2: F(buf0) = gelu(E @ W2 + b2)
  { KD dl2; for (int t=0;t<8;t++){ dl2.p[t]=buf4+(t&1)*32; dl2.ld[t]=64; }
    gemm_mfma<2,0><<<gblk,256,0,stream>>>(dl2, po.W2p, po.b2p, buf0,64,0, N, flags, 0, 0); }
  // TAG2 hops
  spmm<<<sblk,256,0,stream>>>(row_ofs, epack, buf0, buf1, N);
  spmm<<<sblk,256,0,stream>>>(row_ofs, epack, buf1, buf2, N);
  spmm<<<sblk,256,0,stream>>>(row_ofs, epack, buf2, buf3, N);
  // TAG2 concat-GEMM: J(buf4) = gelu([F|G|H|I] @ Wt2 + bt2)
  gemm_mfma<8,0><<<gblk,256,0,stream>>>(dcat, po.Wt2, po.bt2, buf4,64,0, N, flags, 0, 0);
  // L3: Ka = gelu([x|J] @ W3 + b3), two 64-col halves (Ka overlays buf0+buf1)
  gemm_mfma<6,0><<<gblk,256,0,stream>>>(d3, po.W3a, po.b3a, Ka,128,0,  N, flags, xdelta, 0xFu);
  gemm_mfma<6,0><<<gblk,256,0,stream>>>(d3, po.W3b, po.b3b, Ka,128,64, N, flags, xdelta, 0xFu);
  // L4: out = Ka @ W4 + b4
  gemm_mfma<4,1><<<gblk,256,0,stream>>>(d4, po.W4p, po.b4p, d_out,64,0, N, flags, 0, 0);
}